// Round 17
// baseline (181.005 us; speedup 1.0000x reference)
//
#include <hip/hip_runtime.h>
#include <cstddef>
#include <cstdint>

typedef __attribute__((ext_vector_type(8))) short short8;
typedef __attribute__((ext_vector_type(4))) short s16x4;
typedef __attribute__((ext_vector_type(4))) float f32x4;
typedef __attribute__((ext_vector_type(16))) float f32x16;

#define GLOAD_LDS16(gp, lp) __builtin_amdgcn_global_load_lds( \
    (const __attribute__((address_space(1))) void*)(gp),      \
    (__attribute__((address_space(3))) void*)(lp), 16, 0, 0)

__device__ __forceinline__ short f2bf(float f) {
    union { float f; unsigned u; } v; v.f = f;
    unsigned r = v.u + 0x7fffu + ((v.u >> 16) & 1u);
    return (short)(r >> 16);
}

// ---------------------------------------------------------------------------
// Prep: the 5 weight transposes only (f32 [R][C] -> bf16 [C][R]). 352 blocks.
// ---------------------------------------------------------------------------
__global__ __launch_bounds__(256) void prep_kernel(
    const float* __restrict__ Wq, const float* __restrict__ Wk,
    const float* __restrict__ Wv, const float* __restrict__ W1,
    const float* __restrict__ W2,
    short* WqT, short* WkT, short* WvT, short* W1T, short* W2T)
{
    __shared__ short tile[64][68];
    int b2 = blockIdx.x;
    const float* in; short* out; int R, C;
    if (b2 < 16)       { in = Wq; out = WqT; R = 512;  C = 128; }
    else if (b2 < 32)  { in = Wk; out = WkT; R = 512;  C = 128;  b2 -= 16; }
    else if (b2 < 96)  { in = Wv; out = WvT; R = 512;  C = 512;  b2 -= 32; }
    else if (b2 < 224) { in = W1; out = W1T; R = 512;  C = 1024; b2 -= 96; }
    else               { in = W2; out = W2T; R = 1024; C = 512;  b2 -= 224; }
    int nx = C >> 6;
    int r0 = (b2 / nx) * 64, c0 = (b2 % nx) * 64;
    int t = threadIdx.x, tr = t >> 6, tc = t & 63;
#pragma unroll
    for (int i = 0; i < 16; ++i) {
        int r = i * 4 + tr;
        tile[r][tc] = f2bf(in[(size_t)(r0 + r) * C + (c0 + tc)]);
    }
    __syncthreads();
#pragma unroll
    for (int i = 0; i < 16; ++i) {
        int r = i * 4 + tr;
        out[(size_t)(c0 + r) * R + (r0 + tc)] = tile[tc][r];
    }
}

// ---------------------------------------------------------------------------
// Fused q/k/v projection GEMM. DOUBLE-BUFFERED K-loop (T3 minimum-2-phase):
// STAGE(buf^1, t+1) issued BEFORE compute(buf); ONE barrier per K-step.
// A: f32 loads + cvt_pk -> LDS (store-side XOR swizzle). B: global_load_lds.
// Outputs MFMA-fragment-major (frag-RC for q/k, frag-CR for v).
// ---------------------------------------------------------------------------
__global__ __launch_bounds__(256, 2) void proj_gemm(
    const float* __restrict__ x, const float* __restrict__ y,
    const short* __restrict__ WqT, const short* __restrict__ WkT,
    const short* __restrict__ WvT,
    short* __restrict__ qbf, short* __restrict__ kbff, short* __restrict__ vbf)
{
    __shared__ short As[2][128][64];
    __shared__ short Bs[2][128][64];
    int bid = blockIdx.x;
    const float* A; const short* BT; short* outp; int n0, N, mode, mb;
    if (bid < 128)      { A = x; BT = WqT; outp = qbf;  n0 = 0; N = 128; mode = 0; mb = bid; }
    else if (bid < 256) { A = y; BT = WkT; outp = kbff; n0 = 0; N = 128; mode = 0; mb = bid - 128; }
    else { int v2 = bid - 256; A = y; BT = WvT; outp = vbf; n0 = (v2 & 3) << 7; N = 512; mode = 1; mb = v2 >> 2; }
    const int m0 = mb << 7;
    const int K = 512;
    const int t = threadIdx.x, l = t & 63, w = t >> 6;
    const int wm = w >> 1, wn = w & 1;
    const int lo = l & 15, hi = l >> 4;

    f32x4 acc[4][4] = {};
    const int srow = l >> 3;
    const int scg  = (l & 7) ^ (srow & 7);

    // stage tile into buffer `buf` at K-offset kt
    auto STAGE = [&](int buf, int kt) {
#pragma unroll
        for (int i = 0; i < 4; ++i) {
            int seg = w * 4 + i;
            int row = seg * 8 + srow;
            GLOAD_LDS16(BT + (size_t)(n0 + row) * K + kt + scg * 8, &Bs[buf][seg * 8][0]);
        }
#pragma unroll
        for (int i = 0; i < 4; ++i) {
            int c = i * 256 + t;
            int row = c >> 3, ch = c & 7;
            const float* src = A + (size_t)(m0 + row) * K + kt + ch * 8;
            f32x4 u0 = *(const f32x4*)src;
            f32x4 u1 = *(const f32x4*)(src + 4);
            int d0, d1, d2, d3;
            asm("v_cvt_pk_bf16_f32 %0, %1, %2" : "=v"(d0) : "v"(u0[0]), "v"(u0[1]));
            asm("v_cvt_pk_bf16_f32 %0, %1, %2" : "=v"(d1) : "v"(u0[2]), "v"(u0[3]));
            asm("v_cvt_pk_bf16_f32 %0, %1, %2" : "=v"(d2) : "v"(u1[0]), "v"(u1[1]));
            asm("v_cvt_pk_bf16_f32 %0, %1, %2" : "=v"(d3) : "v"(u1[2]), "v"(u1[3]));
            union { int i[4]; short8 v; } uu;
            uu.i[0] = d0; uu.i[1] = d1; uu.i[2] = d2; uu.i[3] = d3;
            *(short8*)&As[buf][row][((ch ^ (row & 7)) * 8)] = uu.v;
        }
    };

    STAGE(0, 0);
    __syncthreads();

    const int nIter = K >> 6;   // 8
    for (int it = 0; it < nIter; ++it) {
        const int buf = it & 1;
        if (it + 1 < nIter) STAGE(buf ^ 1, (it + 1) << 6);   // loads in flight
#pragma unroll
        for (int kk = 0; kk < 2; ++kk) {
            short8 af[4], bfv[4];
            const int rc = ((kk * 4 + hi) ^ (lo & 7)) * 8;
#pragma unroll
            for (int mi = 0; mi < 4; ++mi)
                af[mi] = *(const short8*)&As[buf][wm * 64 + mi * 16 + lo][rc];
#pragma unroll
            for (int ni = 0; ni < 4; ++ni)
                bfv[ni] = *(const short8*)&Bs[buf][wn * 64 + ni * 16 + lo][rc];
            __builtin_amdgcn_s_setprio(1);
#pragma unroll
            for (int mi = 0; mi < 4; ++mi)
#pragma unroll
                for (int ni = 0; ni < 4; ++ni)
                    acc[mi][ni] = __builtin_amdgcn_mfma_f32_16x16x32_bf16(
                        af[mi], bfv[ni], acc[mi][ni], 0, 0, 0);
            __builtin_amdgcn_s_setprio(0);
        }
        __syncthreads();   // one barrier/K-step: drains stage, frees buf
    }

    if (mode == 0) {
#pragma unroll
        for (int mi = 0; mi < 4; ++mi) {
#pragma unroll
            for (int ni = 0; ni < 4; ++ni) {
                int rowb = m0 + wm * 64 + mi * 16 + hi * 4;
                int col  = n0 + wn * 64 + ni * 16 + lo;
                size_t base = ((size_t)(rowb >> 5) * (N >> 4) + (col >> 4)) * 512
                            + ((col & 15) >> 3) * 256 + (rowb & 31) * 8 + (col & 7);
#pragma unroll
                for (int r = 0; r < 4; ++r)
                    outp[base + r * 8] = f2bf(acc[mi][ni][r]);
            }
        }
    } else {
#pragma unroll
        for (int mi = 0; mi < 4; ++mi) {
#pragma unroll
            for (int ni = 0; ni < 4; ++ni) {
                int rowb = m0 + wm * 64 + mi * 16 + hi * 4;
                int col  = n0 + wn * 64 + ni * 16 + lo;
                size_t base = ((size_t)(rowb >> 4) * (N >> 5) + (col >> 5)) * 512
                            + ((rowb & 15) >> 3) * 256 + (col & 31) * 8 + (rowb & 7);
                s16x4 pk;
#pragma unroll
                for (int r = 0; r < 4; ++r) pk[r] = f2bf(acc[mi][ni][r]);
                *(s16x4*)(outp + base) = pk;
            }
        }
    }
}

// ---------------------------------------------------------------------------
// MLP GEMM, DOUBLE-BUFFERED K-loop (1 barrier/K-step), XCD swizzle.
// EPI 2: +bias, exact GELU -> bf16. EPI 3: +bias +resid -> f32.
// ---------------------------------------------------------------------------
template<int EPI>
__global__ __launch_bounds__(256, 2) void gemm_kernel(
    const short* __restrict__ A, const short* __restrict__ BT, void* outv,
    const float* __restrict__ bias, const float* __restrict__ resid,
    int N, int K)
{
    __shared__ short As[2][128][64];
    __shared__ short Bs[2][128][64];
    int bid = blockIdx.x;
    const int cpx = gridDim.x >> 3;
    bid = (bid & 7) * cpx + (bid >> 3);     // XCD swizzle (grid % 8 == 0)
    const int nb = N >> 7;
    const int m0 = (bid / nb) << 7;
    const int n0 = (bid % nb) << 7;
    const int t = threadIdx.x, l = t & 63, w = t >> 6;
    const int wm = w >> 1, wn = w & 1;
    const int lo = l & 15, hi = l >> 4;

    f32x4 acc[4][4] = {};
    const int srow = l >> 3;
    const int scg  = (l & 7) ^ (srow & 7);

    auto STAGE = [&](int buf, int kt) {
#pragma unroll
        for (int i = 0; i < 4; ++i) {
            int seg = w * 4 + i;
            int row = seg * 8 + srow;
            GLOAD_LDS16(A + (size_t)(m0 + row) * K + kt + scg * 8, &As[buf][seg * 8][0]);
        }
#pragma unroll
        for (int i = 0; i < 4; ++i) {
            int seg = w * 4 + i;
            int row = seg * 8 + srow;
            GLOAD_LDS16(BT + (size_t)(n0 + row) * K + kt + scg * 8, &Bs[buf][seg * 8][0]);
        }
    };

    STAGE(0, 0);
    __syncthreads();

    const int nIter = K >> 6;
    for (int it = 0; it < nIter; ++it) {
        const int buf = it & 1;
        if (it + 1 < nIter) STAGE(buf ^ 1, (it + 1) << 6);
#pragma unroll
        for (int kk = 0; kk < 2; ++kk) {
            short8 af[4], bfv[4];
            const int rc = ((kk * 4 + hi) ^ (lo & 7)) * 8;
#pragma unroll
            for (int mi = 0; mi < 4; ++mi)
                af[mi] = *(const short8*)&As[buf][wm * 64 + mi * 16 + lo][rc];
#pragma unroll
            for (int ni = 0; ni < 4; ++ni)
                bfv[ni] = *(const short8*)&Bs[buf][wn * 64 + ni * 16 + lo][rc];
            __builtin_amdgcn_s_setprio(1);
#pragma unroll
            for (int mi = 0; mi < 4; ++mi)
#pragma unroll
                for (int ni = 0; ni < 4; ++ni)
                    acc[mi][ni] = __builtin_amdgcn_mfma_f32_16x16x32_bf16(
                        af[mi], bfv[ni], acc[mi][ni], 0, 0, 0);
            __builtin_amdgcn_s_setprio(0);
        }
        __syncthreads();
    }

#pragma unroll
    for (int mi = 0; mi < 4; ++mi) {
#pragma unroll
        for (int ni = 0; ni < 4; ++ni) {
#pragma unroll
            for (int r = 0; r < 4; ++r) {
                int row = m0 + wm * 64 + mi * 16 + hi * 4 + r;
                int col = n0 + wn * 64 + ni * 16 + lo;
                size_t idx = (size_t)row * N + col;
                float v = acc[mi][ni][r];
                if (EPI == 2) {
                    v += bias[col];
                    v = 0.5f * v * (1.0f + erff(v * 0.70710678118654752f));
                    ((short*)outv)[idx] = f2bf(v);
                } else {
                    v += bias[col] + resid[idx];
                    ((float*)outv)[idx] = v;
                }
            }
        }
    }
}

// ---------------------------------------------------------------------------
// Flash attention + residual + FUSED LayerNorm. Fixed-m softmax (r10 best:
// 69us). 1 barrier/tile; Ps parity double-buffer; JIT V loads.
// ---------------------------------------------------------------------------
__global__ __launch_bounds__(512, 1) void flash_kernel(
    const float* __restrict__ x,    // [8][2048][512] f32
    const short* __restrict__ qbf,  // frag-RC
    const short* __restrict__ kbff, // frag-RC
    const short* __restrict__ vbf,  // frag-CR
    float* __restrict__ xres,       // [8][2048][512] f32
    const float* __restrict__ gamma,
    const float* __restrict__ beta,
    short* __restrict__ hb)         // [16384][512] bf16 (LN output)
{
    __shared__ short Ps[2][2][8][512];   // [buf][qh][key16-blk][lane*8] 32 KB
    __shared__ float lpart[8][32];
    __shared__ float rsum[8][64];
    __shared__ float rsq[8][64];
    __shared__ float murs[2][64];

    const int bid = blockIdx.x;
    const int n = bid & 7;
    const int qtile = bid >> 3;          // 0..31
    const int q0 = qtile << 6;
    const int t = threadIdx.x, l = t & 63, w = t >> 6;
    const int qh = w >> 2, kq = w & 3;
    const int lo5 = l & 31, hi2 = l >> 5;
    const float C1 = 0.08838834764831845f * 1.4426950408889634f; // scale*log2e

    short8 qf[8];
    {
        const short* qp = qbf + (((size_t)(n * 64 + qtile * 2 + qh) * 8) << 9) + l * 8;
#pragma unroll
        for (int s = 0; s < 8; ++s) qf[s] = *(const short8*)(qp + (s << 9));
    }

    f32x16 o00 = {}, o01 = {}, o10 = {}, o11 = {};
    float lp = 0.f;

    const short* kb0 = kbff + (((size_t)(n * 64) * 8) << 9);
    const short* vb0 = vbf + ((((size_t)(n * 128)) * 16 + w * 2) << 9);

    short8 preg0, preg1;

    // ---- prologue: QK(0) + exp2 + pack -> Ps[0] ----
    {
        const short* kp = kb0 + (((size_t)kq * 8) << 9) + l * 8;
        short8 kf[8];
#pragma unroll
        for (int s = 0; s < 8; ++s) kf[s] = *(const short8*)(kp + (s << 9));
        f32x16 sa = {};
        __builtin_amdgcn_s_setprio(1);
#pragma unroll
        for (int s = 0; s < 8; ++s)
            sa = __builtin_amdgcn_mfma_f32_32x32x16_bf16(kf[s], qf[s], sa, 0, 0, 0);
        __builtin_amdgcn_s_setprio(0);
        float lsum = 0.f;
#pragma unroll
        for (int r = 0; r < 16; ++r) {
            float p = exp2f(sa[r] * C1);
            sa[r] = p; lsum += p;
        }
        lp = lsum;
        int wq[8], sx[8];
#pragma unroll
        for (int q2 = 0; q2 < 8; ++q2) {
            int a;
            asm("v_cvt_pk_bf16_f32 %0, %1, %2"
                : "=v"(a) : "v"(sa[2 * q2]), "v"(sa[2 * q2 + 1]));
            wq[q2] = a;
        }
#pragma unroll
        for (int q2 = 0; q2 < 8; ++q2) sx[q2] = __shfl_xor(wq[q2], 32);
        union { int i[4]; short8 v; } u0, u1;
        u0.i[0] = hi2 ? sx[2] : wq[0];
        u0.i[1] = hi2 ? sx[3] : wq[1];
        u0.i[2] = hi2 ? wq[2] : sx[0];
        u0.i[3] = hi2 ? wq[3] : sx[1];
        u1.i[0] = hi2 ? sx[6] : wq[4];
        u1.i[1] = hi2 ? sx[7] : wq[5];
        u1.i[2] = hi2 ? wq[6] : sx[4];
        u1.i[3] = hi2 ? wq[7] : sx[5];
        *(short8*)&Ps[0][qh][kq * 2][l * 8]     = u0.v;
        *(short8*)&Ps[0][qh][kq * 2 + 1][l * 8] = u1.v;
    }

    // ---- main loop: 16 tiles of 128 keys, 1 barrier each ----
    for (int kt2 = 0; kt2 < 16; ++kt2) {
        const bool hn = kt2 < 15;
        const short* vp = vb0 + (((size_t)(kt2 * 128)) << 9) + l * 8;

        short8 kf[8];
        if (hn) {
            const short* kp = kb0 + (((size_t)((kt2 + 1) * 4 + kq) * 8) << 9) + l * 8;
#pragma unroll
            for (int s = 0; s < 8; ++s) kf[s] = *(const short8*)(kp + (s << 9));
        }
        short8 vfa[8];
#pragma unroll
        for (int p = 0; p < 8; ++p)
            vfa[p] = *(const short8*)(vp + (((size_t)((p >> 1) * 16 + (p & 1))) << 9));

        if (hn) {
            f32x16 sa = {};
            __builtin_amdgcn_s_setprio(1);
#pragma unroll
            for (int s = 0; s < 8; ++s)
                sa = __builtin_amdgcn_mfma_f32_32x32x16_bf16(kf[s], qf[s], sa, 0, 0, 0);
            __builtin_amdgcn_s_setprio(0);
            float lsum = 0.f;
#pragma unroll
            for (int r = 0; r < 16; ++r) {
                float p = exp2f(sa[r] * C1);
                sa[r] = p; lsum += p;
            }
            lp += lsum;
            int wq[8], sx[8];
#pragma unroll
            for (int q2 = 0; q2 < 8; ++q2) {
                int a;
                asm("v_cvt_pk_bf16_f32 %0, %1, %2"
                    : "=v"(a) : "v"(sa[2 * q2]), "v"(sa[2 * q2 + 1]));
                wq[q2] = a;
            }
#pragma unroll
            for (int q2 = 0; q2 < 8; ++q2) sx[q2] = __shfl_xor(wq[q2], 32);
            union { int i[4]; short8 v; } u0, u1;
            u0.i[0] = hi2 ? sx[2] : wq[0];
            u0.i[1] = hi2 ? sx[3] : wq[1];
            u0.i[2] = hi2 ? wq[2] : sx[0];
            u0.i[3] = hi2 ? wq[3] : sx[1];
            u1.i[0] = hi2 ? sx[6] : wq[4];
            u1.i[1] = hi2 ? sx[7] : wq[5];
            u1.i[2] = hi2 ? wq[6] : sx[4];
            u1.i[3] = hi2 ? wq[7] : sx[5];
            preg0 = u0.v; preg1 = u1.v;
        }

        __syncthreads();   // window boundary: Ps[t&1] ready

        short8 vfb[8];
#pragma unroll
        for (int p = 0; p < 8; ++p)
            vfb[p] = *(const short8*)(vp + (((size_t)((4 + (p >> 1)) * 16 + (p & 1))) << 9));

        if (hn) {
            const int nb2 = (kt2 + 1) & 1;
            *(short8*)&Ps[nb2][qh][kq * 2][l * 8]     = preg0;
            *(short8*)&Ps[nb2][qh][kq * 2 + 1][l * 8] = preg1;
        }

        const int pb = kt2 & 1;
        __builtin_amdgcn_s_setprio(1);
#pragma unroll
        for (int ks = 0; ks < 4; ++ks) {
            short8 p0 = *(const short8*)&Ps[pb][0][ks][l * 8];
            short8 p1 = *(const short8*)&Ps[pb][1][ks][l * 8];
            o00 = __builtin_amdgcn_mfma_f32_32x32x16_bf16(p0, vfa[ks * 2 + 0], o00, 0, 0, 0);
            o01 = __builtin_amdgcn_mfma_f32_32x32x16_bf16(p0, vfa[ks * 2 + 1], o01, 0, 0, 0);
            o10 = __builtin_amdgcn_mfma_f32_32x32x16_bf16(p1, vfa[ks * 2 + 0], o10, 0, 0, 0);
            o11 = __builtin_amdgcn_mfma_f32_32x32x16_bf16(p1, vfa[ks * 2 + 1], o11, 0, 0, 0);
        }
#pragma unroll
        for (int ks = 4; ks < 8; ++ks) {
            short8 p0 = *(const short8*)&Ps[pb][0][ks][l * 8];
            short8 p1 = *(const short8*)&Ps[pb][1][ks][l * 8];
            o00 = __builtin_amdgcn_mfma_f32_32x32x16_bf16(p0, vfb[(ks - 4) * 2 + 0], o00, 0, 0, 0);
            o01 = __builtin_amdgcn_mfma_f32_32x32x16_bf16(p0, vfb[(ks - 4) * 2 + 1], o01, 0, 0, 0);
            o10 = __builtin_amdgcn_mfma_f32_32x32x16_bf16(p1, vfb[(ks - 4) * 2 + 0], o10, 0, 0, 0);
            o11 = __builtin_amdgcn_mfma_f32_32x32x16_bf16(p1, vfb[(ks - 4) * 2 + 1], o11, 0, 0, 0);
        }
        __builtin_amdgcn_s_setprio(0);
    }

    // ---- epilogue: l-merge, normalize, residual -> xres; fused LN -> hb ----
    float l2 = lp + __shfl_xor(lp, 32);
    if (l < 32) lpart[w][l] = l2;
    __syncthreads();
    float li0 = 1.f / (lpart[0][lo5] + lpart[1][lo5] + lpart[2][lo5] + lpart[3][lo5]);
    float li1 = 1.f / (lpart[4][lo5] + lpart[5][lo5] + lpart[6][lo5] + lpart[7][lo5]);
    const int c0 = w * 64 + lo5;
#pragma unroll
    for (int r = 0; r < 16; ++r) {
        int qr = (r & 3) + 8 * (r >> 2) + 4 * hi2;
        float ir0 = __shfl(li0, qr);
        float ir1 = __shfl(li1, qr);
        size_t b0 = ((size_t)(n * 2048 + q0 + qr) << 9) + c0;
        size_t b1 = ((size_t)(n * 2048 + q0 + 32 + qr) << 9) + c0;
        float v00 = x[b0]      + o00[r] * ir0;
        float v01 = x[b0 + 32] + o01[r] * ir0;
        float v10 = x[b1]      + o10[r] * ir1;
        float v11 = x[b1 + 32] + o11[r] * ir1;
        xres[b0] = v00; xres[b0 + 32] = v01;
        xres[b1] = v10; xres[b1 + 32] = v11;
        o00[r] = v00; o01[r] = v01; o10[r] = v10; o11[r] = v11;
        float s0 = v00 + v01, sq0 = v00 * v00 + v01 * v01;
        float s1 = v10 + v11, sq1 = v10 * v10 + v11 * v11;
#pragma unroll
        for (int mm = 1; mm < 32; mm <<= 1) {
            s0 += __shfl_xor(s0, mm); sq0 += __shfl_xor(sq0, mm);
            s1 += __shfl_xor(s1, mm); sq1 += __shfl_xor(sq1, mm);
        }
        if (lo5 == 0) {
            rsum[w][qr] = s0;      rsq[w][qr] = sq0;
            rsum[w][32 + qr] = s1; rsq[w][32 + qr] = sq1;
        }
    }
    __syncthreads();
    if (t < 64) {
        float s = 0.f, qq = 0.f;
#pragma unroll
        for (int ww = 0; ww < 8; ++ww) { s += rsum[ww][t]; qq += rsq[ww][t]; }
        float mu = s * (1.0f / 512.0f);
        float var = qq * (1.0f / 512.0f) - mu * mu;
        murs[0][t] = mu;
        murs[1][t] = rsqrtf(var + 1e-5f);
    }
    __syncthreads();
    const float g0 = gamma[c0], g1 = gamma[c0 + 32];
    const float e0 = beta[c0],  e1 = beta[c0 + 32];
#pragma unroll
    for (int r = 0; r < 16; ++r) {
        int qr = (r & 3) + 8 * (r >> 2) + 4 * hi2;
        float mu0 = murs[0][qr],      rs0 = murs[1][qr];
        float mu1 = murs[0][32 + qr], rs1 = murs[1][32 + qr];
        size_t h0 = ((size_t)(n * 2048 + q0 + qr) << 9) + c0;
        size_t h1 = ((size_t)(n * 2048 + q0 + 32 + qr) << 9) + c0;
        hb[h0]      = f2bf((o00[r] - mu0) * rs0 * g0 + e0);
        hb[h0 + 32] = f2bf((o01[r] - mu0) * rs0 * g1 + e1);
        hb[h1]      = f2bf((o10[r] - mu1) * rs1 * g0 + e0);
        hb[h1 + 32] = f2bf((o11[r] - mu1) * rs1 * g1 + e1);
    }
}

// ---------------------------------------------------------------------------
extern "C" void kernel_launch(void* const* d_in, const int* in_sizes, int n_in,
                              void* d_out, int out_size, void* d_ws, size_t ws_size,
                              hipStream_t stream)
{
    const float* x     = (const float*)d_in[0];
    const float* y     = (const float*)d_in[1];
    const float* Wq    = (const float*)d_in[2];
    const float* Wk    = (const float*)d_in[3];
    const float* Wv    = (const float*)d_in[4];
    const float* gamma = (const float*)d_in[5];
    const float* beta  = (const float*)d_in[6];
    const float* W1    = (const float*)d_in[7];
    const float* b1    = (const float*)d_in[8];
    const float* W2    = (const float*)d_in[9];
    const float* b2    = (const float*)d_in[10];
    float* out = (float*)d_out;

    char* ws = (char*)d_ws;
    size_t off = 0;
    auto alloc = [&](size_t bytes) -> void* {
        void* p = ws + off;
        off += (bytes + 255) & ~(size_t)255;
        return p;
    };
    short* WqT  = (short*)alloc((size_t)128 * 512 * 2);
    short* WkT  = (short*)alloc((size_t)128 * 512 * 2);
    short* WvT  = (short*)alloc((size_t)512 * 512 * 2);
    short* W1T  = (short*)alloc((size_t)1024 * 512 * 2);
    short* W2T  = (short*)alloc((size_t)512 * 1024 * 2);
    short* qbf  = (short*)alloc((size_t)16384 * 128 * 2);   // frag-RC
    short* kbff = (short*)alloc((size_t)16384 * 128 * 2);   // frag-RC
    short* vbf  = (short*)alloc((size_t)16384 * 512 * 2);   // frag-CR
    short* hb   = (short*)alloc((size_t)16384 * 512 * 2);
    short* gb   = (short*)alloc((size_t)16384 * 1024 * 2);

    // 1. prep: weight transposes only
    prep_kernel<<<352, 256, 0, stream>>>(Wq, Wk, Wv, W1, W2,
                                         WqT, WkT, WvT, W1T, W2T);
    // 2. fused q/k/v projections (dbuf, 1 barrier/K-step) -> frag-major
    proj_gemm<<<768, 256, 0, stream>>>(x, y, WqT, WkT, WvT, qbf, kbff, vbf);
    // 3. attention + residual + fused LN -> xres(d_out), hb
    flash_kernel<<<256, 512, 0, stream>>>(x, qbf, kbff, vbf, out, gamma, beta, hb);
    // 4. MLP (dbuf GEMMs)
    gemm_kernel<2><<<1024, 256, 0, stream>>>(hb, W1T, gb, b1, nullptr, 1024, 512);
    gemm_kernel<3><<<512,  256, 0, stream>>>(gb, W2T, out, b2, out, 512, 1024);

    (void)in_sizes; (void)n_in; (void)out_size; (void)ws_size;
}